// Round 1
// baseline (5543.005 us; speedup 1.0000x reference)
//
#include <hip/hip_runtime.h>
#include <stdint.h>

typedef uint32_t u32;
typedef __bf16 bf16;
typedef bf16 bf16x8 __attribute__((ext_vector_type(8)));
typedef float f32x4 __attribute__((ext_vector_type(4)));

#define B_ 256
#define T_ 256
#define H_ 1024
#define G_ 4096   // 4*H
#define NI_ 2048

// Dropout variant: 1 = partitionable threefry (modern JAX default), 0 = legacy split-iota
#define DROPOUT_PARTITIONABLE 1

// ---- workspace layout ----
static constexpr size_t OFF_W2T = 0;                           // [2][4096 cols grouped][1024 k] bf16
static constexpr size_t SZ_W2T  = (size_t)2 * G_ * H_ * 2;     // 16 MB
static constexpr size_t OFF_H   = OFF_W2T + SZ_W2T;            // [2 pp][2 dir][B][H] bf16
static constexpr size_t SZ_H    = (size_t)2 * 2 * B_ * H_ * 2; // 2 MB
static constexpr size_t OFF_C   = OFF_H + SZ_H;                // [2 dir][B][H] f32
static constexpr size_t SZ_C    = (size_t)2 * B_ * H_ * 4;     // 2 MB
static constexpr size_t OFF_LENS= OFF_C + SZ_C;                // 256 i32
static constexpr size_t OFF_RL  = OFF_LENS + 1024;             // 256 f32

__device__ __forceinline__ float bf2f(uint16_t b){ return __uint_as_float(((u32)b) << 16); }
__device__ __forceinline__ uint16_t f2bf(float f){
  u32 u = __float_as_uint(f);
  return (uint16_t)((u + 0x7fffu + ((u >> 16) & 1u)) >> 16);  // RNE
}
__device__ __forceinline__ float sigm(float x){ return 1.f / (1.f + __expf(-x)); }
__device__ __forceinline__ float tanh_(float x){ return 1.f - 2.f / (__expf(2.f * x) + 1.f); }

// threefry2x32, matches jax rotations [13,15,26,6] / [17,29,16,24]
__device__ __forceinline__ void threefry(u32 k0, u32 k1, u32 x0, u32 x1, u32& o0, u32& o1){
  u32 ks2 = k0 ^ k1 ^ 0x1BD11BDAu;
  x0 += k0; x1 += k1;
#define TFR(r) { x0 += x1; x1 = (x1 << r) | (x1 >> (32 - r)); x1 ^= x0; }
  TFR(13) TFR(15) TFR(26) TFR(6)  x0 += k1;  x1 += ks2 + 1u;
  TFR(17) TFR(29) TFR(16) TFR(24) x0 += ks2; x1 += k0 + 2u;
  TFR(13) TFR(15) TFR(26) TFR(6)  x0 += k0;  x1 += k1 + 3u;
  TFR(17) TFR(29) TFR(16) TFR(24) x0 += k1;  x1 += ks2 + 4u;
  TFR(13) TFR(15) TFR(26) TFR(6)  x0 += ks2; x1 += k0 + 5u;
#undef TFR
  o0 = x0; o1 = x1;
}

// keep-mask for flat index idx into (2,B,H); key = (0,42); p = 0.5 (keep iff top bit of bits == 0)
__device__ __forceinline__ bool keep_mask(u32 idx){
#if DROPOUT_PARTITIONABLE
  u32 o0, o1; threefry(0u, 42u, 0u, idx, o0, o1);
  u32 bits = o0 ^ o1;
#else
  const u32 half = (2u * B_ * H_) / 2u;   // 262144
  u32 a = (idx < half) ? idx : (idx - half);
  u32 b = a + half;
  u32 o0, o1; threefry(0u, 42u, a, b, o0, o1);
  u32 bits = (idx < half) ? o0 : o1;
#endif
  return (bits & 0x80000000u) == 0u;
}

// ---- prep: transpose + convert Whh (K=1024, 4096) f32 -> W2T[d][vcg][k] bf16
// vcg groups the 4 gate strips per 32-hcol block: col = strip*1024 + n*32 + c -> vcg = n*128 + strip*32 + c
__global__ __launch_bounds__(256) void k_prep_w(const float* __restrict__ whh_f,
                                                const float* __restrict__ whh_b,
                                                uint16_t* __restrict__ w2t){
  int bid = blockIdx.x;
  int d  = bid >> 12;        // 4096 blocks per dir
  int r  = bid & 4095;
  int kt = r >> 7;           // 32 k-tiles of 32
  int ct = r & 127;          // 128 col-tiles of 32
  const float* W = d ? whh_b : whh_f;
  __shared__ float tile[32][33];
  int tid = threadIdx.x;
  int lr = tid >> 5, lc = tid & 31;
#pragma unroll
  for (int i = 0; i < 4; i++)
    tile[lr + i*8][lc] = W[(size_t)(kt*32 + lr + i*8) * G_ + ct*32 + lc];
  __syncthreads();
  int colLocal = tid >> 3, kseg = tid & 7;
  int col = ct*32 + colLocal;
  int strip = col >> 10;
  int within = col & 1023;
  int n = within >> 5;
  int c = within & 31;
  int vcg = n*128 + strip*32 + c;
  size_t base = ((size_t)d * G_ + vcg) * H_ + kt*32 + kseg*4;
  u32 w0 = (u32)f2bf(tile[kseg*4+0][colLocal]) | ((u32)f2bf(tile[kseg*4+1][colLocal]) << 16);
  u32 w1 = (u32)f2bf(tile[kseg*4+2][colLocal]) | ((u32)f2bf(tile[kseg*4+3][colLocal]) << 16);
  uint2 v; v.x = w0; v.y = w1;
  *(uint2*)(w2t + base) = v;
}

// ---- init: zero h(pp=0, both dirs) + c; block 256 computes lens
__global__ __launch_bounds__(256) void k_init(uint16_t* __restrict__ hbuf, float* __restrict__ cbuf,
                                              int* __restrict__ lens, const int* __restrict__ items){
  int bid = blockIdx.x, tid = threadIdx.x;
  if (bid == 256){
    int cnt = 0;
    for (int t = 0; t < T_; t++) cnt += (items[(size_t)tid * T_ + t] != 0) ? 1 : 0;
    lens[tid] = cnt;
    return;
  }
  size_t g = (size_t)bid * 256 + tid;                 // 65536 threads
  ((uint4*)hbuf)[g] = make_uint4(0,0,0,0);            // 1 MB  = pp0 region
  ((float4*)cbuf)[g*2]   = make_float4(0,0,0,0);      // 2 MB
  ((float4*)cbuf)[g*2+1] = make_float4(0,0,0,0);
}

// ---- one LSTM time step, both directions.
// grid 256 = dir(2) x mtile(4, 64 rows) x ngroup(32, 32 hcols -> 128 gate cols)
__global__ __launch_bounds__(256) void k_step(
    const int* __restrict__ items, const int* __restrict__ actions,
    const float* __restrict__ wt_f, const float* __restrict__ wt_b,
    const float* __restrict__ bias_f, const float* __restrict__ bias_b,
    const uint16_t* __restrict__ w2t, uint16_t* __restrict__ hbuf,
    float* __restrict__ cbuf, const int* __restrict__ lens, int s)
{
  int bid = blockIdx.x;
  int d = bid >> 7;
  int m = (bid >> 5) & 3;
  int n = bid & 31;
  int t = d ? (T_ - 1 - s) : s;
  int pp = s & 1;
  const uint16_t* hin  = hbuf + ((size_t)(pp*2 + d)) * B_ * H_;
  uint16_t*       hout = hbuf + ((size_t)((pp^1)*2 + d)) * B_ * H_;
  float* cdir = cbuf + (size_t)d * B_ * H_;
  const float* wt   = d ? wt_b : wt_f;
  const float* bias = d ? bias_b : bias_f;
  const uint16_t* wslice = w2t + ((size_t)d * G_ + n*128) * H_;  // [128 vcol][1024 k]

  __shared__ __align__(16) uint16_t Asm[64][72];
  __shared__ __align__(16) uint16_t Bsm[128][72];
  __shared__ float gsm[64][128];
  __shared__ int s_item[64], s_act[64], s_len[64];

  int tid = threadIdx.x;
  int b0 = m * 64;
  if (tid < 64){
    int b = b0 + tid;
    s_item[tid] = items[(size_t)b * T_ + t];
    s_act[tid]  = actions[(size_t)b * T_ + t];
    s_len[tid]  = lens[b];
  }
  __syncthreads();

  // Phase X: gsm[r][vcol] = Wt[item] + Wt[2048+act] + bias (f32)
#pragma unroll 4
  for (int it = 0; it < 32; it++){
    int flat = it*256 + tid;          // 8192 = 64 x 128
    int r = flat >> 7, vcol = flat & 127;
    int strip = vcol >> 5, cc = vcol & 31;
    int gcol = strip*1024 + n*32 + cc;
    float x = wt[(size_t)s_item[r] * G_ + gcol]
            + wt[(size_t)(2048 + s_act[r]) * G_ + gcol]
            + bias[gcol];
    gsm[r][vcol] = x;
  }

  int l = tid & 63;
  int w = tid >> 6;
  int wm = w >> 1, wn = w & 1;        // wave grid 2(M) x 2(N)
  f32x4 acc[2][4];
#pragma unroll
  for (int mi = 0; mi < 2; mi++)
#pragma unroll
    for (int ni = 0; ni < 4; ni++)
      acc[mi][ni] = (f32x4){0.f, 0.f, 0.f, 0.f};

  int lrow = l & 15;
  int lk   = (l >> 4) * 8;

  for (int k0 = 0; k0 < H_; k0 += 64){
    __syncthreads();
    // stage A: h tile 64 x 64 bf16
#pragma unroll
    for (int i = 0; i < 2; i++){
      int flat = i*256 + tid;
      int r = flat >> 3, seg = flat & 7;
      *(uint4*)(&Asm[r][seg*8]) = *(const uint4*)(hin + (size_t)(b0 + r) * H_ + k0 + seg*8);
    }
    // stage B: weights (already [vcol][k]) 128 x 64 bf16
#pragma unroll
    for (int i = 0; i < 4; i++){
      int flat = i*256 + tid;
      int vcol = flat >> 3, seg = flat & 7;
      *(uint4*)(&Bsm[vcol][seg*8]) = *(const uint4*)(wslice + (size_t)vcol * H_ + k0 + seg*8);
    }
    __syncthreads();
#pragma unroll
    for (int kk = 0; kk < 64; kk += 32){
      bf16x8 a0 = *(bf16x8*)(&Asm[wm*32 + lrow][kk + lk]);
      bf16x8 a1 = *(bf16x8*)(&Asm[wm*32 + 16 + lrow][kk + lk]);
#pragma unroll
      for (int ni = 0; ni < 4; ni++){
        bf16x8 bb = *(bf16x8*)(&Bsm[wn*64 + ni*16 + lrow][kk + lk]);
        acc[0][ni] = __builtin_amdgcn_mfma_f32_16x16x32_bf16(a0, bb, acc[0][ni], 0, 0, 0);
        acc[1][ni] = __builtin_amdgcn_mfma_f32_16x16x32_bf16(a1, bb, acc[1][ni], 0, 0, 0);
      }
    }
  }
  __syncthreads();
  // add accumulators into gsm (C/D layout: col = l&15, row = (l>>4)*4 + reg)
#pragma unroll
  for (int mi = 0; mi < 2; mi++)
#pragma unroll
    for (int ni = 0; ni < 4; ni++)
#pragma unroll
      for (int r4 = 0; r4 < 4; r4++){
        int row  = wm*32 + mi*16 + (l >> 4)*4 + r4;
        int vcol = wn*64 + ni*16 + lrow;
        gsm[row][vcol] += acc[mi][ni][r4];
      }
  __syncthreads();
  // gates: strips 0..3 of vcol are i,f,g,o for hcol = n*32 + j
#pragma unroll
  for (int it = 0; it < 8; it++){
    int flat = it*256 + tid;          // 2048 = 64 x 32
    int r = flat >> 5, j = flat & 31;
    int b = b0 + r;
    int hcol = n*32 + j;
    size_t idx = (size_t)b * H_ + hcol;
    uint16_t hval;
    if (t < s_len[r]){
      float ip = gsm[r][j];
      float fp = gsm[r][32 + j];
      float gp = gsm[r][64 + j];
      float op = gsm[r][96 + j];
      float cn = sigm(fp) * cdir[idx] + sigm(ip) * tanh_(gp);
      cdir[idx] = cn;
      hval = f2bf(sigm(op) * tanh_(cn));
    } else {
      hval = hin[idx];                // frozen
    }
    hout[idx] = hval;
  }
}

// ---- FC + per-row loss. One block per batch row.
__global__ __launch_bounds__(256) void k_fc(const uint16_t* __restrict__ hfin,  // pp0: [dir][B][H]
    const float* __restrict__ wfc, const float* __restrict__ bfc,
    const int* __restrict__ targets, float* __restrict__ rowloss){
  int b = blockIdx.x, tid = threadIdx.x;
  float a0 = 0.f, a1 = 0.f;
  for (int jj = tid; jj < 2*H_; jj += 256){
    int d = jj >> 10, j = jj & 1023;
    float h = bf2f(hfin[(size_t)d * B_ * H_ + (size_t)b * H_ + j]);
    u32 idx = (u32)(d * (B_ * H_) + b * H_ + j);
    float feat = keep_mask(idx) ? (2.f * h) : 0.f;
    a0 += feat * wfc[jj*2 + 0];
    a1 += feat * wfc[jj*2 + 1];
  }
#pragma unroll
  for (int off = 32; off > 0; off >>= 1){
    a0 += __shfl_down(a0, off, 64);
    a1 += __shfl_down(a1, off, 64);
  }
  __shared__ float r0[4], r1[4];
  if ((tid & 63) == 0){ r0[tid >> 6] = a0; r1[tid >> 6] = a1; }
  __syncthreads();
  if (tid == 0){
    float l0 = r0[0]+r0[1]+r0[2]+r0[3] + bfc[0];
    float l1 = r1[0]+r1[1]+r1[2]+r1[3] + bfc[1];
    float mx = fmaxf(l0, l1);
    float lse = mx + logf(__expf(l0 - mx) + __expf(l1 - mx));
    rowloss[b] = lse - (targets[b] ? l1 : l0);
  }
}

__global__ __launch_bounds__(256) void k_loss(const float* __restrict__ rowloss, float* __restrict__ out){
  int tid = threadIdx.x;
  float v = rowloss[tid];
#pragma unroll
  for (int off = 32; off > 0; off >>= 1) v += __shfl_down(v, off, 64);
  __shared__ float r[4];
  if ((tid & 63) == 0) r[tid >> 6] = v;
  __syncthreads();
  if (tid == 0) out[0] = (r[0] + r[1] + r[2] + r[3]) * (1.f / B_);
}

extern "C" void kernel_launch(void* const* d_in, const int* in_sizes, int n_in,
                              void* d_out, int out_size, void* d_ws, size_t ws_size,
                              hipStream_t stream){
  (void)in_sizes; (void)n_in; (void)out_size; (void)ws_size;
  const int*   items   = (const int*)  d_in[0];
  const int*   actions = (const int*)  d_in[1];
  const int*   targets = (const int*)  d_in[2];
  const float* wt_f    = (const float*)d_in[3];
  const float* whh_f   = (const float*)d_in[4];
  const float* b_f     = (const float*)d_in[5];
  const float* wt_b    = (const float*)d_in[6];
  const float* whh_b   = (const float*)d_in[7];
  const float* b_b     = (const float*)d_in[8];
  const float* wfc     = (const float*)d_in[9];
  const float* bfc     = (const float*)d_in[10];

  char* ws = (char*)d_ws;
  uint16_t* w2t   = (uint16_t*)(ws + OFF_W2T);
  uint16_t* hbuf  = (uint16_t*)(ws + OFF_H);
  float*    cbuf  = (float*)   (ws + OFF_C);
  int*      lens  = (int*)     (ws + OFF_LENS);
  float*    rlbuf = (float*)   (ws + OFF_RL);

  hipLaunchKernelGGL(k_prep_w, dim3(8192), dim3(256), 0, stream, whh_f, whh_b, w2t);
  hipLaunchKernelGGL(k_init,   dim3(257),  dim3(256), 0, stream, hbuf, cbuf, lens, items);
  for (int s = 0; s < T_; s++)
    hipLaunchKernelGGL(k_step, dim3(256), dim3(256), 0, stream,
                       items, actions, wt_f, wt_b, b_f, b_b, w2t, hbuf, cbuf, lens, s);
  hipLaunchKernelGGL(k_fc,   dim3(256), dim3(256), 0, stream, hbuf, wfc, bfc, targets, rlbuf);
  hipLaunchKernelGGL(k_loss, dim3(1),   dim3(256), 0, stream, rlbuf, (float*)d_out);
}